// Round 2
// baseline (364.989 us; speedup 1.0000x reference)
//
#include <hip/hip_runtime.h>

#define B_ 128
#define T_ 2048
#define H_ 128
#define WPAD 136  // 128 + 8 pad (bf16 elems)

typedef __attribute__((ext_vector_type(8))) short short8;
typedef __attribute__((ext_vector_type(4))) float f32x4;

__device__ __forceinline__ unsigned short f2b(float f) {
    unsigned int u = __float_as_uint(f);
    u += 0x7fffu + ((u >> 16) & 1u);   // RNE
    return (unsigned short)(u >> 16);
}
__device__ __forceinline__ short8 pack8(const float4 x, const float4 y) {
    short8 r;
    r[0] = (short)f2b(x.x); r[1] = (short)f2b(x.y);
    r[2] = (short)f2b(x.z); r[3] = (short)f2b(x.w);
    r[4] = (short)f2b(y.x); r[5] = (short)f2b(y.y);
    r[6] = (short)f2b(y.z); r[7] = (short)f2b(y.w);
    return r;
}
__device__ __forceinline__ float tanh_fast(float x) {
    x = fminf(fmaxf(x, -20.f), 20.f);
    float e = __expf(2.f * x);
    return (e - 1.f) / (e + 1.f);
}

// ---------------- Phase 1: energy[b,t] = W_a . tanh(W_h hp + W_d hd) + b_a ----
// GEMM rows = b*T+t (M=262144), N=128 (o), K=256 (hp|hd). fp32 in, bf16 MFMA.
__global__ __launch_bounds__(256) void energy_kernel(
    const float* __restrict__ Hp,
    const float* __restrict__ Hd,
    const float* __restrict__ Wh,
    const float* __restrict__ Wd,
    const float* __restrict__ Wa,
    const float* __restrict__ ba_p,
    float* __restrict__ energy,
    int ntiles)
{
    __shared__ unsigned short Whs[H_ * WPAD];
    __shared__ unsigned short Wds[H_ * WPAD];
    __shared__ float Was[H_];

    const int tid = threadIdx.x;

    // stage W_h, W_d (fp32 [o][h]) into padded bf16 LDS
    for (int i = tid; i < (H_ * H_) / 4; i += 256) {
        int row = i >> 5;          // 32 float4 per row
        int c4  = (i & 31) * 4;
        float4 wh = *(const float4*)&Wh[row * H_ + c4];
        float4 wd = *(const float4*)&Wd[row * H_ + c4];
        uint2 ph, pd;
        ph.x = (unsigned)f2b(wh.x) | ((unsigned)f2b(wh.y) << 16);
        ph.y = (unsigned)f2b(wh.z) | ((unsigned)f2b(wh.w) << 16);
        pd.x = (unsigned)f2b(wd.x) | ((unsigned)f2b(wd.y) << 16);
        pd.y = (unsigned)f2b(wd.z) | ((unsigned)f2b(wd.w) << 16);
        *(uint2*)&Whs[row * WPAD + c4] = ph;
        *(uint2*)&Wds[row * WPAD + c4] = pd;
    }
    if (tid < H_) Was[tid] = Wa[tid];
    __syncthreads();

    const float ba = ba_p[0];

    const int wave = tid >> 6;
    const int lane = tid & 63;
    const int l15  = lane & 15;
    const int lq   = lane >> 4;    // 0..3

    for (int tile = blockIdx.x; tile < ntiles; tile += gridDim.x) {
        const int row_base = tile * 64 + wave * 16;

        // A fragments: A[m=l15][k = kt*32 + lq*8 + j]
        short8 afrag[8];
        const float* ap = Hp + (size_t)(row_base + l15) * H_ + lq * 8;
        const float* ad = Hd + (size_t)(row_base + l15) * H_ + lq * 8;
        #pragma unroll
        for (int kt = 0; kt < 4; kt++) {
            float4 x0 = *(const float4*)(ap + kt * 32);
            float4 x1 = *(const float4*)(ap + kt * 32 + 4);
            afrag[kt] = pack8(x0, x1);
            float4 y0 = *(const float4*)(ad + kt * 32);
            float4 y1 = *(const float4*)(ad + kt * 32 + 4);
            afrag[kt + 4] = pack8(y0, y1);
        }

        float ep[4] = {0.f, 0.f, 0.f, 0.f};
        #pragma unroll
        for (int nt = 0; nt < 8; nt++) {
            const int n = nt * 16 + l15;   // output channel o == this lane's C column
            f32x4 acc = {0.f, 0.f, 0.f, 0.f};
            #pragma unroll
            for (int kt = 0; kt < 4; kt++) {
                short8 bf = *(const short8*)&Whs[n * WPAD + kt * 32 + lq * 8];
                acc = __builtin_amdgcn_mfma_f32_16x16x32_bf16(afrag[kt], bf, acc, 0, 0, 0);
            }
            #pragma unroll
            for (int kt = 0; kt < 4; kt++) {
                short8 bf = *(const short8*)&Wds[n * WPAD + kt * 32 + lq * 8];
                acc = __builtin_amdgcn_mfma_f32_16x16x32_bf16(afrag[kt + 4], bf, acc, 0, 0, 0);
            }
            const float wa = Was[n];
            // C/D: col = lane&15 (== n), row = lq*4 + r
            #pragma unroll
            for (int r = 0; r < 4; r++) ep[r] += tanh_fast(acc[r]) * wa;
        }
        #pragma unroll
        for (int m = 1; m < 16; m <<= 1) {
            #pragma unroll
            for (int r = 0; r < 4; r++) ep[r] += __shfl_xor(ep[r], m, 64);
        }
        if (l15 == 0) {
            #pragma unroll
            for (int r = 0; r < 4; r++)
                energy[row_base + lq * 4 + r] = ep[r] + ba;
        }
    }
}

// ---------------- Phase 2a: softmax over T -> alpha (fp32) ----------------
// One block per batch; 256 threads, 8 t's per thread.
__global__ __launch_bounds__(256) void softmax_kernel(
    const float* __restrict__ accw,
    const float* __restrict__ beta_p,
    const float* __restrict__ energy,
    float* __restrict__ out_alpha)
{
    __shared__ float sred[8];
    const int b    = blockIdx.x;
    const int tid  = threadIdx.x;
    const int lane = tid & 63;
    const int wid  = tid >> 6;   // 0..3

    const float beta_pos = log1pf(__expf(beta_p[0]));

    float av[8], ev[8];
    float amax = -1e30f;
    #pragma unroll
    for (int i = 0; i < 8; i++) {
        int t = i * 256 + tid;
        av[i] = accw[b * T_ + t];
        ev[i] = energy[b * T_ + t];
        amax = fmaxf(amax, av[i]);
    }
    for (int m = 32; m >= 1; m >>= 1) amax = fmaxf(amax, __shfl_xor(amax, m, 64));
    if (lane == 0) sred[wid] = amax;
    __syncthreads();
    if (tid == 0)
        sred[4] = fmaxf(fmaxf(sred[0], sred[1]), fmaxf(sred[2], sred[3]));
    __syncthreads();
    const float invd = beta_pos / fmaxf(sred[4], 1e-6f);

    float sv[8], smax = -1e30f;
    #pragma unroll
    for (int i = 0; i < 8; i++) {
        sv[i] = ev[i] * (1.f + av[i] * invd);
        smax = fmaxf(smax, sv[i]);
    }
    for (int m = 32; m >= 1; m >>= 1) smax = fmaxf(smax, __shfl_xor(smax, m, 64));
    __syncthreads();
    if (lane == 0) sred[wid] = smax;
    __syncthreads();
    if (tid == 0)
        sred[5] = fmaxf(fmaxf(sred[0], sred[1]), fmaxf(sred[2], sred[3]));
    __syncthreads();
    const float smax_all = sred[5];

    float p[8], psum = 0.f;
    #pragma unroll
    for (int i = 0; i < 8; i++) { p[i] = __expf(sv[i] - smax_all); psum += p[i]; }
    for (int m = 32; m >= 1; m >>= 1) psum += __shfl_xor(psum, m, 64);
    __syncthreads();
    if (lane == 0) sred[wid] = psum;
    __syncthreads();
    if (tid == 0)
        sred[6] = sred[0] + sred[1] + sred[2] + sred[3];
    __syncthreads();
    const float invS = 1.f / sred[6];

    #pragma unroll
    for (int i = 0; i < 8; i++)
        out_alpha[b * T_ + i * 256 + tid] = p[i] * invS;
}

// ---------------- Phase 2b: partial context over t-slices ----------------
// grid = B*4 blocks; block s of batch b covers t in [s*512, s*512+512).
__global__ __launch_bounds__(256) void ctx_partial_kernel(
    const float* __restrict__ Hp,
    const float* __restrict__ alpha,
    float* __restrict__ cpart)   // [B][4][H]
{
    __shared__ float red[32 * H_];   // 16 KB
    __shared__ float red2[2 * H_];

    const int s   = blockIdx.x & 3;
    const int b   = blockIdx.x >> 2;
    const int tid = threadIdx.x;
    const int trow = tid >> 3;    // 0..31
    const int hseg = tid & 7;     // 16 floats each

    float c[16];
    #pragma unroll
    for (int j = 0; j < 16; j++) c[j] = 0.f;

    const float* base = Hp + ((size_t)b * T_ + s * 512) * H_ + hseg * 16;
    const float* al   = alpha + b * T_ + s * 512;

    for (int it = 0; it < 16; it++) {
        int t = it * 32 + trow;
        float a = al[t];
        const float* p0 = base + (size_t)t * H_;
        float4 v0 = *(const float4*)(p0);
        float4 v1 = *(const float4*)(p0 + 4);
        float4 v2 = *(const float4*)(p0 + 8);
        float4 v3 = *(const float4*)(p0 + 12);
        c[0]  += a * v0.x; c[1]  += a * v0.y; c[2]  += a * v0.z; c[3]  += a * v0.w;
        c[4]  += a * v1.x; c[5]  += a * v1.y; c[6]  += a * v1.z; c[7]  += a * v1.w;
        c[8]  += a * v2.x; c[9]  += a * v2.y; c[10] += a * v2.z; c[11] += a * v2.w;
        c[12] += a * v3.x; c[13] += a * v3.y; c[14] += a * v3.z; c[15] += a * v3.w;
    }
    #pragma unroll
    for (int j = 0; j < 16; j++) red[trow * H_ + hseg * 16 + j] = c[j];
    __syncthreads();
    {
        int h = tid & 127, half = tid >> 7;
        float ssum = 0.f;
        for (int r = half * 16; r < half * 16 + 16; r++) ssum += red[r * H_ + h];
        red2[half * H_ + h] = ssum;
    }
    __syncthreads();
    if (tid < H_)
        cpart[(b * 4 + s) * H_ + tid] = red2[tid] + red2[H_ + tid];
}

__global__ __launch_bounds__(256) void ctx_reduce_kernel(
    const float* __restrict__ cpart, float* __restrict__ out_ctx)
{
    int i = blockIdx.x * 256 + threadIdx.x;   // i < B*H
    if (i < B_ * H_) {
        int b = i >> 7, h = i & 127;
        out_ctx[i] = cpart[(b * 4 + 0) * H_ + h] + cpart[(b * 4 + 1) * H_ + h]
                   + cpart[(b * 4 + 2) * H_ + h] + cpart[(b * 4 + 3) * H_ + h];
    }
}

extern "C" void kernel_launch(void* const* d_in, const int* in_sizes, int n_in,
                              void* d_out, int out_size, void* d_ws, size_t ws_size,
                              hipStream_t stream) {
    const float* Hp   = (const float*)d_in[0];
    const float* Hd   = (const float*)d_in[1];
    const float* accw = (const float*)d_in[2];
    const float* Wh   = (const float*)d_in[3];
    const float* Wd   = (const float*)d_in[4];
    const float* Wa   = (const float*)d_in[5];
    const float* ba   = (const float*)d_in[6];
    const float* beta = (const float*)d_in[7];

    float* energy_ws = (float*)d_ws;                 // B*T fp32 = 1 MB
    float* cpart_ws  = energy_ws + B_ * T_;          // B*4*H fp32 = 8 KB

    float* out_ctx   = (float*)d_out;                // [B,H]
    float* out_alpha = out_ctx + B_ * H_;            // [B,T]

    const int ntiles = (B_ * T_) / 64;   // 4096
    energy_kernel<<<1024, 256, 0, stream>>>(Hp, Hd, Wh, Wd, Wa, ba, energy_ws, ntiles);
    softmax_kernel<<<B_, 256, 0, stream>>>(accw, beta, energy_ws, out_alpha);
    ctx_partial_kernel<<<B_ * 4, 256, 0, stream>>>(Hp, out_alpha, cpart_ws);
    ctx_reduce_kernel<<<(B_ * H_ + 255) / 256, 256, 0, stream>>>(cpart_ws, out_ctx);
}